// Round 2
// baseline (1367.475 us; speedup 1.0000x reference)
//
#include <hip/hip_runtime.h>
#include <hip/hip_bf16.h>
#include <math.h>

typedef __attribute__((ext_vector_type(8))) short bf16x8;
typedef __attribute__((ext_vector_type(4))) float f32x4;

#define DEVI __device__ __forceinline__

static constexpr int Bg  = 512;   // graphs
static constexpr int NPG = 256;   // nodes per graph
static constexpr int NN  = Bg * NPG;
static constexpr int PSD = 512;
static constexpr int RD  = 64;

DEVI unsigned short f2bf(float x) {
    union { float f; unsigned u; } v; v.f = x;
    unsigned r = v.u + 0x7FFFu + ((v.u >> 16) & 1u);   // RNE
    return (unsigned short)(r >> 16);
}
DEVI float sigmoidf_(float x) { return 1.0f / (1.0f + expf(-x)); }

// ---------------- K0a: 51x128 embedding tables --------------------------
// v=0: EmbA = rel_emb @ A_w[512:576]      v=1: T1h = sh @ C_w[1536:1600]
// v=2: T2h = sh @ C_w[1600:1664]          v=3: T1t = st @ E_w[1536:1600]
// v=4: T2t = st @ E_w[1600:1664]
__launch_bounds__(128)
__global__ void k_tables(const float* __restrict__ rel_emb, const float* __restrict__ sh,
                         const float* __restrict__ st,
                         const float* __restrict__ A_w, const float* __restrict__ C_w,
                         const float* __restrict__ E_w,
                         float* __restrict__ EmbA, float* __restrict__ T1h, float* __restrict__ T2h,
                         float* __restrict__ T1t, float* __restrict__ T2t) {
    int r = blockIdx.x, v = blockIdx.y, f = threadIdx.x;
    const float* emb; const float* W; float* out; int off;
    switch (v) {
        case 0:  emb = rel_emb; W = A_w; off = 512;  out = EmbA; break;
        case 1:  emb = sh;      W = C_w; off = 1536; out = T1h;  break;
        case 2:  emb = sh;      W = C_w; off = 1600; out = T2h;  break;
        case 3:  emb = st;      W = E_w; off = 1536; out = T1t;  break;
        default: emb = st;      W = E_w; off = 1600; out = T2t;  break;
    }
    float s = 0.f;
    for (int k = 0; k < RD; ++k) s += emb[r * RD + k] * W[(off + k) * 128 + f];
    out[r * 128 + f] = s;
}

// ---------------- K0b: WT[j][k] bf16 = concat(A_w,C_w,E_w)[k][j] --------
__launch_bounds__(256)
__global__ void k_pack_wt(const float* __restrict__ A_w, const float* __restrict__ C_w,
                          const float* __restrict__ E_w, unsigned short* __restrict__ WT) {
    int idx = blockIdx.x * 256 + threadIdx.x;   // 384*512
    int j = idx >> 9, k = idx & 511;
    float v = (j < 128) ? A_w[k * 128 + j]
            : (j < 256) ? C_w[k * 128 + (j - 128)]
                        : E_w[k * 128 + (j - 256)];
    WT[j * 512 + k] = f2bf(v);
}

// ---------------- K0c: htwT[o][k] bf16 = ht_w[k][o] ---------------------
__launch_bounds__(256)
__global__ void k_pack_htw(const float* __restrict__ ht_w, unsigned short* __restrict__ htwT) {
    int idx = blockIdx.x * 256 + threadIdx.x;   // 3200*512, k-major for coalesced read
    int k = idx >> 9, o = idx & 511;
    htwT[o * 3200 + k] = f2bf(ht_w[idx]);
}

// ---------------- K0d: gather hN / tN -----------------------------------
__launch_bounds__(512)
__global__ void k_gather_ht(const float* __restrict__ flat, const int* __restrict__ head_ids,
                            const int* __restrict__ tail_ids,
                            float* __restrict__ hN, float* __restrict__ tN) {
    int b = blockIdx.x, t = threadIdx.x;
    int h = head_ids[b], tl = tail_ids[b];
    hN[b * 512 + t] = flat[h * 512 + t];
    tN[b * 512 + t] = flat[tl * 512 + t];
}

// ---------------- K1: per-graph head/tail contributions ------------------
// gHT[b] = hN@C_w[512:1024] + tN@C_w[1024:1536] + C_b
// dHT[b] = tN@E_w[512:1024] + hN@E_w[1024:1536] + E_b
__launch_bounds__(256)
__global__ void k_ht_gates(const float* __restrict__ hN, const float* __restrict__ tN,
                           const float* __restrict__ C_w, const float* __restrict__ C_b,
                           const float* __restrict__ E_w, const float* __restrict__ E_b,
                           float* __restrict__ gHT, float* __restrict__ dHT) {
    __shared__ float hn[2][512], tn[2][512];
    const int g0 = blockIdx.x * 2;
    const int t = threadIdx.x;
    for (int i = t; i < 1024; i += 256) {
        hn[i >> 9][i & 511] = hN[g0 * 512 + i];
        tn[i >> 9][i & 511] = tN[g0 * 512 + i];
    }
    __syncthreads();
    const int f = t & 127;
    const int path = t >> 7;           // 0: gamma (C), 1: delta (E); wave-uniform
    const float* W = path ? E_w : C_w;
    float acc0 = 0.f, acc1 = 0.f;
    for (int k = 0; k < 512; ++k) {
        float w1 = W[(512 + k) * 128 + f];
        float w2 = W[(1024 + k) * 128 + f];
        if (path == 0) {
            acc0 += hn[0][k] * w1 + tn[0][k] * w2;
            acc1 += hn[1][k] * w1 + tn[1][k] * w2;
        } else {
            acc0 += tn[0][k] * w1 + hn[0][k] * w2;
            acc1 += tn[1][k] * w1 + hn[1][k] * w2;
        }
    }
    float bias = (path ? E_b : C_b)[f];
    float* outp = path ? dHT : gHT;
    outp[(g0 + 0) * 128 + f] = acc0 + bias;
    outp[(g0 + 1) * 128 + f] = acc1 + bias;
}

// ---------------- K2: big gate kernel (MFMA) -----------------------------
// flat[N,512] @ WT^T[512,384] -> +adds -> relu -> 128->4 -> sigmoid -> weights
__launch_bounds__(256)
__global__ void k_gates(const float* __restrict__ flat, const unsigned short* __restrict__ WT,
                        const float* __restrict__ EmbA,
                        const float* __restrict__ T1h, const float* __restrict__ T2h,
                        const float* __restrict__ T1t, const float* __restrict__ T2t,
                        const float* __restrict__ gHT, const float* __restrict__ dHT,
                        const float* __restrict__ A_b, const float* __restrict__ B_w,
                        const float* __restrict__ B_b,
                        const float* __restrict__ Dm_w, const float* __restrict__ Dm_b,
                        const float* __restrict__ G_w, const float* __restrict__ G_b,
                        const int* __restrict__ t_label, const int* __restrict__ hs_type,
                        const int* __restrict__ ts_type, const int* __restrict__ graph_ids,
                        const float* __restrict__ head_sister, const float* __restrict__ tail_sister,
                        float4* __restrict__ w0, float4* __restrict__ w1, float4* __restrict__ w2) {
    const int lane = threadIdx.x & 63;
    const int wave = threadIdx.x >> 6;
    const int c   = lane & 15;
    const int grp = lane >> 4;
    const int nodeBase = blockIdx.x * 64 + wave * 16;

    f32x4 acc[24];
#pragma unroll
    for (int t = 0; t < 24; ++t) { acc[t][0] = 0.f; acc[t][1] = 0.f; acc[t][2] = 0.f; acc[t][3] = 0.f; }

    const float* arow = flat + (nodeBase + c) * 512 + grp * 8;
    const unsigned short* brow = WT + c * 512 + grp * 8;

    for (int ks = 0; ks < 16; ++ks) {
        const int k0 = ks * 32;
        float4 a0 = *(const float4*)(arow + k0);
        float4 a1 = *(const float4*)(arow + k0 + 4);
        bf16x8 af;
        af[0] = (short)f2bf(a0.x); af[1] = (short)f2bf(a0.y);
        af[2] = (short)f2bf(a0.z); af[3] = (short)f2bf(a0.w);
        af[4] = (short)f2bf(a1.x); af[5] = (short)f2bf(a1.y);
        af[6] = (short)f2bf(a1.z); af[7] = (short)f2bf(a1.w);
        const unsigned short* bp = brow + k0;
#pragma unroll
        for (int t = 0; t < 24; ++t) {
            bf16x8 bv = *(const bf16x8*)(bp + t * 8192);   // (t*16)*512
            acc[t] = __builtin_amdgcn_mfma_f32_16x16x32_bf16(af, bv, acc[t], 0, 0, 0);
        }
    }

#pragma unroll
    for (int r = 0; r < 4; ++r) {
        const int node = nodeBase + grp * 4 + r;
        const int g   = graph_ids[node];
        const int tl  = t_label[node];
        const int hst = hs_type[node];
        const int tst = ts_type[node];
        float pB0=0,pB1=0,pB2=0,pB3=0, pG0=0,pG1=0,pG2=0,pG3=0, pD0=0,pD1=0,pD2=0,pD3=0;
#pragma unroll
        for (int t = 0; t < 8; ++t) {
            const int f = t * 16 + c;
            float xb = acc[t][r]      + A_b[f] + EmbA[tl * 128 + f];
            float xg = acc[8 + t][r]  + gHT[g * 128 + f] + T1h[hst * 128 + f] + T2h[tl * 128 + f];
            float xd = acc[16 + t][r] + dHT[g * 128 + f] + T1t[tst * 128 + f] + T2t[tl * 128 + f];
            xb = fmaxf(xb, 0.f); xg = fmaxf(xg, 0.f); xd = fmaxf(xd, 0.f);
            const float4 wB = *(const float4*)(B_w  + f * 4);
            const float4 wG = *(const float4*)(Dm_w + f * 4);
            const float4 wD = *(const float4*)(G_w  + f * 4);
            pB0 += xb * wB.x; pB1 += xb * wB.y; pB2 += xb * wB.z; pB3 += xb * wB.w;
            pG0 += xg * wG.x; pG1 += xg * wG.y; pG2 += xg * wG.z; pG3 += xg * wG.w;
            pD0 += xd * wD.x; pD1 += xd * wD.y; pD2 += xd * wD.z; pD3 += xd * wD.w;
        }
#pragma unroll
        for (int m = 1; m < 16; m <<= 1) {
            pB0 += __shfl_xor(pB0, m); pB1 += __shfl_xor(pB1, m);
            pB2 += __shfl_xor(pB2, m); pB3 += __shfl_xor(pB3, m);
            pG0 += __shfl_xor(pG0, m); pG1 += __shfl_xor(pG1, m);
            pG2 += __shfl_xor(pG2, m); pG3 += __shfl_xor(pG3, m);
            pD0 += __shfl_xor(pD0, m); pD1 += __shfl_xor(pD1, m);
            pD2 += __shfl_xor(pD2, m); pD3 += __shfl_xor(pD3, m);
        }
        if (c == 0) {
            const float4 hs = *(const float4*)(head_sister + node * 4);
            const float4 ts = *(const float4*)(tail_sister + node * 4);
            float4 o0, o1, o2;
            o0.x = sigmoidf_(pB0 + B_b[0]);  o0.y = sigmoidf_(pB1 + B_b[1]);
            o0.z = sigmoidf_(pB2 + B_b[2]);  o0.w = sigmoidf_(pB3 + B_b[3]);
            o1.x = sigmoidf_(pG0 + Dm_b[0]) * hs.x; o1.y = sigmoidf_(pG1 + Dm_b[1]) * hs.y;
            o1.z = sigmoidf_(pG2 + Dm_b[2]) * hs.z; o1.w = sigmoidf_(pG3 + Dm_b[3]) * hs.w;
            o2.x = sigmoidf_(pD0 + G_b[0]) * ts.x;  o2.y = sigmoidf_(pD1 + G_b[1]) * ts.y;
            o2.z = sigmoidf_(pD2 + G_b[2]) * ts.z;  o2.w = sigmoidf_(pD3 + G_b[3]) * ts.w;
            w0[node] = o0; w1[node] = o1; w2[node] = o2;
        }
    }
}

// ---------------- K3: weighted segment means -----------------------------
__launch_bounds__(256)
__global__ void k_wmean(const float* __restrict__ flat,
                        const float4* __restrict__ w0, const float4* __restrict__ w1,
                        const float4* __restrict__ w2,
                        float* __restrict__ g_out, float* __restrict__ ghs, float* __restrict__ gts) {
    __shared__ float wl0[256][4], wl1[256][4], wl2[256][4];
    __shared__ float den[12];
    __shared__ float4 red0[256], red1[256], red2[256];
    const int g = blockIdx.x, t = threadIdx.x;
    {
        float4 a = w0[g * 256 + t], b = w1[g * 256 + t], cc = w2[g * 256 + t];
        wl0[t][0]=a.x; wl0[t][1]=a.y; wl0[t][2]=a.z; wl0[t][3]=a.w;
        wl1[t][0]=b.x; wl1[t][1]=b.y; wl1[t][2]=b.z; wl1[t][3]=b.w;
        wl2[t][0]=cc.x; wl2[t][1]=cc.y; wl2[t][2]=cc.z; wl2[t][3]=cc.w;
    }
    __syncthreads();
    if (t < 12) {
        const int which = t >> 2, ll = t & 3;
        const float (*W)[4] = (which == 0) ? wl0 : (which == 1) ? wl1 : wl2;
        float s = 0.f;
        for (int n = 0; n < 256; ++n) s += W[n][ll];
        den[t] = s;
    }
    const int q = t & 127;     // feature quad (4 floats)
    const int half = t >> 7;   // node parity
    const int l = q >> 5;      // layer index
    float4 s0 = make_float4(0,0,0,0), s1 = make_float4(0,0,0,0), s2 = make_float4(0,0,0,0);
    const float* base = flat + g * 256 * 512 + q * 4;
    for (int n = half; n < 256; n += 2) {
        float4 x = *(const float4*)(base + n * 512);
        float a = wl0[n][l], b = wl1[n][l], cc = wl2[n][l];
        s0.x += a * x.x;  s0.y += a * x.y;  s0.z += a * x.z;  s0.w += a * x.w;
        s1.x += b * x.x;  s1.y += b * x.y;  s1.z += b * x.z;  s1.w += b * x.w;
        s2.x += cc * x.x; s2.y += cc * x.y; s2.z += cc * x.z; s2.w += cc * x.w;
    }
    red0[t] = s0; red1[t] = s1; red2[t] = s2;
    __syncthreads();
    if (t < 128) {
        float4 a0 = red0[t], a1 = red0[t + 128];
        float4 b0 = red1[t], b1 = red1[t + 128];
        float4 c0 = red2[t], c1 = red2[t + 128];
        float d0 = 1.f / den[l], d1 = 1.f / den[4 + l], d2 = 1.f / den[8 + l];
        float* po = g_out + g * 512 + t * 4;
        po[0] = (a0.x + a1.x) * d0; po[1] = (a0.y + a1.y) * d0;
        po[2] = (a0.z + a1.z) * d0; po[3] = (a0.w + a1.w) * d0;
        float* ph = ghs + g * 512 + t * 4;
        ph[0] = (b0.x + b1.x) * d1; ph[1] = (b0.y + b1.y) * d1;
        ph[2] = (b0.z + b1.z) * d1; ph[3] = (b0.w + b1.w) * d1;
        float* pt = gts + g * 512 + t * 4;
        pt[0] = (c0.x + c1.x) * d2; pt[1] = (c0.y + c1.y) * d2;
        pt[2] = (c0.z + c1.z) * d2; pt[3] = (c0.w + c1.w) * d2;
    }
}

// ---------------- K4: build g_ht (bf16) ----------------------------------
__launch_bounds__(256)
__global__ void k_build_ght(const float* __restrict__ ghs, const float* __restrict__ gts,
                            const float* __restrict__ hN, const float* __restrict__ tN,
                            const float* __restrict__ sh, const float* __restrict__ st,
                            const int* __restrict__ rel_labels, unsigned short* __restrict__ ght) {
    const int g = blockIdx.x, t = threadIdx.x;
    const int rel = rel_labels[g];
    for (int i = t; i < 3200; i += 256) {
        float v;
        if      (i < 512)  v = ghs[g * 512 + i] * hN[g * 512 + i];
        else if (i < 1024) { int j = i - 512;  v = gts[g * 512 + j] * tN[g * 512 + j]; }
        else if (i < 1536) v = ghs[g * 512 + i - 1024];
        else if (i < 2048) v = gts[g * 512 + i - 1536];
        else if (i < 2560) v = hN[g * 512 + i - 2048];
        else if (i < 3072) v = tN[g * 512 + i - 2560];
        else if (i < 3136) v = sh[rel * 64 + i - 3072];
        else               v = st[rel * 64 + i - 3136];
        ght[g * 3200 + i] = f2bf(v);
    }
}

// ---------------- K5: ht GEMM (MFMA): [512,3200]@[3200,512] + relu -------
__launch_bounds__(256)
__global__ void k_ht_gemm(const unsigned short* __restrict__ ght, const unsigned short* __restrict__ htwT,
                          const float* __restrict__ ht_b, float* __restrict__ ht_out) {
    const int lane = threadIdx.x & 63;
    const int wave = threadIdx.x >> 6;
    const int c = lane & 15, grp = lane >> 4;
    const int rowBase = blockIdx.x * 64 + wave * 16;
    const int colBase = blockIdx.y * 64;
    const unsigned short* ap = ght  + (rowBase + c) * 3200 + grp * 8;
    const unsigned short* bp = htwT + (colBase + c) * 3200 + grp * 8;
    f32x4 acc[4];
#pragma unroll
    for (int t = 0; t < 4; ++t) { acc[t][0]=0.f; acc[t][1]=0.f; acc[t][2]=0.f; acc[t][3]=0.f; }
#pragma unroll 2
    for (int ks = 0; ks < 100; ++ks) {
        bf16x8 af = *(const bf16x8*)(ap + ks * 32);
#pragma unroll
        for (int t = 0; t < 4; ++t) {
            bf16x8 bv = *(const bf16x8*)(bp + ks * 32 + t * (16 * 3200));
            acc[t] = __builtin_amdgcn_mfma_f32_16x16x32_bf16(af, bv, acc[t], 0, 0, 0);
        }
    }
#pragma unroll
    for (int t = 0; t < 4; ++t) {
        const int col = colBase + t * 16 + c;
        const float bias = ht_b[col];
#pragma unroll
        for (int r = 0; r < 4; ++r) {
            const int row = rowBase + grp * 4 + r;
            ht_out[row * 512 + col] = fmaxf(acc[t][r] + bias, 0.f);
        }
    }
}

// ---------------- K6: fc + out -------------------------------------------
__launch_bounds__(128)
__global__ void k_fc(const float* __restrict__ g_out, const float* __restrict__ hN,
                     const float* __restrict__ tN, const float* __restrict__ ht_out,
                     const float* __restrict__ rel_emb, const int* __restrict__ rel_labels,
                     const float* __restrict__ fc_w, const float* __restrict__ fc_b,
                     const float* __restrict__ out_w, const float* __restrict__ out_b,
                     float* __restrict__ outp) {
    __shared__ float red[128];
    const int g = blockIdx.x, t = threadIdx.x;
    const int o = t & 15, ch = t >> 4;    // 8 chunks of 264
    const int rel = rel_labels[g];
    float p = 0.f;
    for (int i = ch * 264; i < ch * 264 + 264; ++i) {
        float v;
        if      (i < 512)  v = g_out[g * 512 + i];
        else if (i < 1024) v = hN[g * 512 + i - 512];
        else if (i < 1536) v = tN[g * 512 + i - 1024];
        else if (i < 2048) v = ht_out[g * 512 + i - 1536];
        else               v = rel_emb[rel * 64 + i - 2048];
        p += v * fc_w[i * 16 + o];
    }
    red[t] = p;
    __syncthreads();
    if (t < 16) {
        float s = fc_b[t];
        for (int c2 = 0; c2 < 8; ++c2) s += red[c2 * 16 + t];
        red[t] = fmaxf(s, 0.f) * out_w[t];
    }
    __syncthreads();
    if (t == 0) {
        float s = out_b[0];
        for (int i = 0; i < 16; ++i) s += red[i];
        outp[g] = s;
    }
}

// ---------------- launch --------------------------------------------------
extern "C" void kernel_launch(void* const* d_in, const int* in_sizes, int n_in,
                              void* d_out, int out_size, void* d_ws, size_t ws_size,
                              hipStream_t stream) {
    const float* node_repr   = (const float*)d_in[0];
    const float* head_sister = (const float*)d_in[1];
    const float* tail_sister = (const float*)d_in[2];
    const int*   t_label     = (const int*)d_in[3];
    const int*   hs_type     = (const int*)d_in[4];
    const int*   ts_type     = (const int*)d_in[5];
    const int*   graph_ids   = (const int*)d_in[6];
    const int*   head_ids    = (const int*)d_in[7];
    const int*   tail_ids    = (const int*)d_in[8];
    const int*   rel_labels  = (const int*)d_in[9];
    const float* rel_emb     = (const float*)d_in[10];
    const float* sim_head    = (const float*)d_in[11];
    const float* sim_tail    = (const float*)d_in[12];
    const float* A_w  = (const float*)d_in[13];
    const float* A_b  = (const float*)d_in[14];
    const float* B_w  = (const float*)d_in[15];
    const float* B_b  = (const float*)d_in[16];
    const float* C_w  = (const float*)d_in[17];
    const float* C_b  = (const float*)d_in[18];
    const float* Dm_w = (const float*)d_in[19];
    const float* Dm_b = (const float*)d_in[20];
    const float* E_w  = (const float*)d_in[21];
    const float* E_b  = (const float*)d_in[22];
    const float* G_w  = (const float*)d_in[23];
    const float* G_b  = (const float*)d_in[24];
    const float* ht_w = (const float*)d_in[25];
    const float* ht_b = (const float*)d_in[26];
    const float* fc_w = (const float*)d_in[27];
    const float* fc_b = (const float*)d_in[28];
    const float* out_w = (const float*)d_in[29];
    const float* out_b = (const float*)d_in[30];
    float* out = (float*)d_out;

    char* ws = (char*)d_ws;
    size_t off = 0;
    auto take = [&](size_t bytes) -> void* {
        void* p = ws + off;
        off += (bytes + 255) & ~(size_t)255;
        return p;
    };
    unsigned short* WT   = (unsigned short*)take((size_t)384 * 512 * 2);
    unsigned short* htwT = (unsigned short*)take((size_t)512 * 3200 * 2);
    float* EmbA = (float*)take(51 * 128 * 4);
    float* T1h  = (float*)take(51 * 128 * 4);
    float* T2h  = (float*)take(51 * 128 * 4);
    float* T1t  = (float*)take(51 * 128 * 4);
    float* T2t  = (float*)take(51 * 128 * 4);
    float* hN   = (float*)take((size_t)Bg * 512 * 4);
    float* tN   = (float*)take((size_t)Bg * 512 * 4);
    float* gHT  = (float*)take((size_t)Bg * 128 * 4);
    float* dHT  = (float*)take((size_t)Bg * 128 * 4);
    float4* w0  = (float4*)take((size_t)NN * 16);
    float4* w1  = (float4*)take((size_t)NN * 16);
    float4* w2  = (float4*)take((size_t)NN * 16);
    float* g_out_ = (float*)take((size_t)Bg * 512 * 4);
    float* ghs  = (float*)take((size_t)Bg * 512 * 4);
    float* gts  = (float*)take((size_t)Bg * 512 * 4);
    unsigned short* ght = (unsigned short*)take((size_t)Bg * 3200 * 2);
    float* ht_out = (float*)take((size_t)Bg * 512 * 4);
    (void)ws_size; (void)in_sizes; (void)n_in; (void)out_size;

    k_tables<<<dim3(51, 5), 128, 0, stream>>>(rel_emb, sim_head, sim_tail, A_w, C_w, E_w,
                                              EmbA, T1h, T2h, T1t, T2t);
    k_pack_wt<<<768, 256, 0, stream>>>(A_w, C_w, E_w, WT);
    k_pack_htw<<<6400, 256, 0, stream>>>(ht_w, htwT);
    k_gather_ht<<<Bg, 512, 0, stream>>>(node_repr, head_ids, tail_ids, hN, tN);
    k_ht_gates<<<Bg / 2, 256, 0, stream>>>(hN, tN, C_w, C_b, E_w, E_b, gHT, dHT);
    k_gates<<<NN / 64, 256, 0, stream>>>(node_repr, WT, EmbA, T1h, T2h, T1t, T2t, gHT, dHT,
                                         A_b, B_w, B_b, Dm_w, Dm_b, G_w, G_b,
                                         t_label, hs_type, ts_type, graph_ids,
                                         head_sister, tail_sister, w0, w1, w2);
    k_wmean<<<Bg, 256, 0, stream>>>(node_repr, w0, w1, w2, g_out_, ghs, gts);
    k_build_ght<<<Bg, 256, 0, stream>>>(ghs, gts, hN, tN, sim_head, sim_tail, rel_labels, ght);
    k_ht_gemm<<<dim3(8, 8), 256, 0, stream>>>(ght, htwT, ht_b, ht_out);
    k_fc<<<Bg, 128, 0, stream>>>(g_out_, hN, tN, ht_out, rel_emb, rel_labels,
                                 fc_w, fc_b, out_w, out_b, out);
}

// Round 8
// 1054.803 us; speedup vs baseline: 1.2964x; 1.2964x over previous
//
#include <hip/hip_runtime.h>
#include <hip/hip_bf16.h>
#include <math.h>

typedef __attribute__((ext_vector_type(8))) short bf16x8;
typedef __attribute__((ext_vector_type(4))) float f32x4;

#define DEVI __device__ __forceinline__

static constexpr int Bg  = 512;   // graphs
static constexpr int NPG = 256;   // nodes per graph
static constexpr int NN  = Bg * NPG;
static constexpr int RD  = 64;

DEVI unsigned short f2bf(float x) {
    union { float f; unsigned u; } v; v.f = x;
    unsigned r = v.u + 0x7FFFu + ((v.u >> 16) & 1u);   // RNE
    return (unsigned short)(r >> 16);
}
DEVI float bf2f(unsigned short u) {
    union { unsigned u; float f; } v; v.u = ((unsigned)u) << 16; return v.f;
}
DEVI float sigmoidf_(float x) { return 1.0f / (1.0f + expf(-x)); }

// ---------------- K0a: 51x128 embedding tables --------------------------
__launch_bounds__(128)
__global__ void k_tables(const float* __restrict__ rel_emb, const float* __restrict__ sh,
                         const float* __restrict__ st,
                         const float* __restrict__ A_w, const float* __restrict__ C_w,
                         const float* __restrict__ E_w,
                         float* __restrict__ EmbA, float* __restrict__ T1h, float* __restrict__ T2h,
                         float* __restrict__ T1t, float* __restrict__ T2t) {
    int r = blockIdx.x, v = blockIdx.y, f = threadIdx.x;
    const float* emb; const float* W; float* out; int off;
    switch (v) {
        case 0:  emb = rel_emb; W = A_w; off = 512;  out = EmbA; break;
        case 1:  emb = sh;      W = C_w; off = 1536; out = T1h;  break;
        case 2:  emb = sh;      W = C_w; off = 1600; out = T2h;  break;
        case 3:  emb = st;      W = E_w; off = 1536; out = T1t;  break;
        default: emb = st;      W = E_w; off = 1600; out = T2t;  break;
    }
    float s = 0.f;
    for (int k = 0; k < RD; ++k) s += emb[r * RD + k] * W[(off + k) * 128 + f];
    out[r * 128 + f] = s;
}

// ---------------- K0b: WT[j][k] bf16 = concat(A_w,C_w,E_w)[k][j] --------
__launch_bounds__(256)
__global__ void k_pack_wt(const float* __restrict__ A_w, const float* __restrict__ C_w,
                          const float* __restrict__ E_w, unsigned short* __restrict__ WT) {
    int idx = blockIdx.x * 256 + threadIdx.x;   // 384*512
    int j = idx >> 9, k = idx & 511;
    float v = (j < 128) ? A_w[k * 128 + j]
            : (j < 256) ? C_w[k * 128 + (j - 128)]
                        : E_w[k * 128 + (j - 256)];
    WT[j * 512 + k] = f2bf(v);
}

// ---------------- K0c: htwT[o][k] bf16 = ht_w[k][o] (tiled transpose) ----
__launch_bounds__(256)
__global__ void k_pack_htw(const float* __restrict__ ht_w, unsigned short* __restrict__ htwT) {
    __shared__ float tile[32][33];
    const int k0 = blockIdx.x * 32, o0 = blockIdx.y * 32;
    const int i = threadIdx.x >> 5, j = threadIdx.x & 31;
    for (int r = i; r < 32; r += 8) tile[r][j] = ht_w[(size_t)(k0 + r) * 512 + o0 + j];
    __syncthreads();
    for (int r = i; r < 32; r += 8) htwT[(size_t)(o0 + r) * 3200 + k0 + j] = f2bf(tile[j][r]);
}

// ---------------- K0d: gather hN / tN -----------------------------------
__launch_bounds__(512)
__global__ void k_gather_ht(const float* __restrict__ flat, const int* __restrict__ head_ids,
                            const int* __restrict__ tail_ids,
                            float* __restrict__ hN, float* __restrict__ tN) {
    int b = blockIdx.x, t = threadIdx.x;
    int h = head_ids[b], tl = tail_ids[b];
    hN[b * 512 + t] = flat[h * 512 + t];
    tN[b * 512 + t] = flat[tl * 512 + t];
}

// ---------------- K1: per-graph head/tail contributions ------------------
__launch_bounds__(256)
__global__ void k_ht_gates(const float* __restrict__ hN, const float* __restrict__ tN,
                           const float* __restrict__ C_w, const float* __restrict__ C_b,
                           const float* __restrict__ E_w, const float* __restrict__ E_b,
                           float* __restrict__ gHT, float* __restrict__ dHT) {
    __shared__ float hn[2][512], tn[2][512];
    const int g0 = blockIdx.x * 2;
    const int t = threadIdx.x;
    for (int i = t; i < 1024; i += 256) {
        hn[i >> 9][i & 511] = hN[g0 * 512 + i];
        tn[i >> 9][i & 511] = tN[g0 * 512 + i];
    }
    __syncthreads();
    const int f = t & 127;
    const int path = t >> 7;
    const float* W = path ? E_w : C_w;
    float acc0 = 0.f, acc1 = 0.f;
    for (int k = 0; k < 512; ++k) {
        float w1 = W[(512 + k) * 128 + f];
        float w2 = W[(1024 + k) * 128 + f];
        if (path == 0) {
            acc0 += hn[0][k] * w1 + tn[0][k] * w2;
            acc1 += hn[1][k] * w1 + tn[1][k] * w2;
        } else {
            acc0 += tn[0][k] * w1 + hn[0][k] * w2;
            acc1 += tn[1][k] * w1 + hn[1][k] * w2;
        }
    }
    float bias = (path ? E_b : C_b)[f];
    float* outp = path ? dHT : gHT;
    outp[(g0 + 0) * 128 + f] = acc0 + bias;
    outp[(g0 + 1) * 128 + f] = acc1 + bias;
}

// ---------------- K2: fused gates + weighted-mean partials ----------------
// Block: 64 nodes (quarter graph). Stage x (bf16, swizzled) in LDS once.
// For p in {beta,gamma,delta}: MFMA vs WT slice, epilogue -> gate weights wv.
// Then partial num/den sums from LDS x, atomicAdd to per-graph buffers.
__global__ __launch_bounds__(256, 2)
void k_gates_fused(const float* __restrict__ flat, const unsigned short* __restrict__ WT,
                   const float* __restrict__ EmbA,
                   const float* __restrict__ T1h, const float* __restrict__ T2h,
                   const float* __restrict__ T1t, const float* __restrict__ T2t,
                   const float* __restrict__ gHT, const float* __restrict__ dHT,
                   const float* __restrict__ A_b, const float* __restrict__ B_w,
                   const float* __restrict__ B_b,
                   const float* __restrict__ Dm_w, const float* __restrict__ Dm_b,
                   const float* __restrict__ G_w, const float* __restrict__ G_b,
                   const int* __restrict__ t_label, const int* __restrict__ hs_type,
                   const int* __restrict__ ts_type,
                   const float* __restrict__ head_sister, const float* __restrict__ tail_sister,
                   float* __restrict__ num, float* __restrict__ den) {
    __shared__ unsigned short xa[64 * 512];    // 64 KB, XOR-swizzled bf16
    __shared__ float wv[3][64][4];             // gate weights per path/node/layer

    const int t    = threadIdx.x;
    const int lane = t & 63;
    const int wave = t >> 6;
    const int c    = lane & 15;
    const int grp  = lane >> 4;
    const int nb0  = blockIdx.x * 64;          // first node of this block
    const int g    = nb0 >> 8;                 // graph id (256 nodes/graph)

    // ---- stage x: f32 -> bf16, swizzled rows of 1024 B ----
    {
        const float4* src = (const float4*)(flat + (size_t)nb0 * 512);
#pragma unroll
        for (int j = 0; j < 32; ++j) {
            int idx = j * 256 + t;             // float4 index in [0, 8192)
            int row = idx >> 7, c4 = idx & 127;
            float4 v = src[idx];
            ushort4 b;
            b.x = f2bf(v.x); b.y = f2bf(v.y); b.z = f2bf(v.z); b.w = f2bf(v.w);
            *(ushort4*)((char*)xa + row * 1024 + ((c4 * 8) ^ ((row & 7) << 4))) = b;
        }
    }
    __syncthreads();

    const int nodeStrip = wave * 16;
    const char* arow = (const char*)xa + (nodeStrip + c) * 1024;
    const int asw = (c & 7) << 4;

    // per-node labels for epilogue
    int tl4[4], hst4[4], tst4[4];
#pragma unroll
    for (int r = 0; r < 4; ++r) {
        int node = nb0 + nodeStrip + grp * 4 + r;
        tl4[r]  = t_label[node];
        hst4[r] = hs_type[node];
        tst4[r] = ts_type[node];
    }

    for (int p = 0; p < 3; ++p) {
        f32x4 acc[8];
#pragma unroll
        for (int tt = 0; tt < 8; ++tt) { acc[tt][0]=0.f; acc[tt][1]=0.f; acc[tt][2]=0.f; acc[tt][3]=0.f; }

        const unsigned short* bp = WT + ((size_t)(p * 128 + c)) * 512 + grp * 8;
#pragma unroll
        for (int ks = 0; ks < 16; ++ks) {
            bf16x8 af = *(const bf16x8*)(arow + ((ks * 64 + grp * 16) ^ asw));
#pragma unroll
            for (int tt = 0; tt < 8; ++tt) {
                bf16x8 bv = *(const bf16x8*)(bp + tt * 8192 + ks * 32);
                acc[tt] = __builtin_amdgcn_mfma_f32_16x16x32_bf16(af, bv, acc[tt], 0, 0, 0);
            }
        }

        const float* W2 = (p == 0) ? B_w  : (p == 1) ? Dm_w : G_w;
        const float* b2 = (p == 0) ? B_b  : (p == 1) ? Dm_b : G_b;
        const float* base0 = (p == 0) ? A_b : (p == 1) ? (gHT + g * 128) : (dHT + g * 128);

#pragma unroll
        for (int r = 0; r < 4; ++r) {
            const int nb = nodeStrip + grp * 4 + r;
            const int node = nb0 + nb;
            const float* tab1 = (p == 0) ? (EmbA + tl4[r] * 128)
                              : (p == 1) ? (T1h + hst4[r] * 128)
                                         : (T1t + tst4[r] * 128);
            const float* tab2 = (p == 1) ? (T2h + tl4[r] * 128)
                              : (p == 2) ? (T2t + tl4[r] * 128) : nullptr;
            float p0 = 0.f, p1 = 0.f, p2 = 0.f, p3 = 0.f;
#pragma unroll
            for (int tt = 0; tt < 8; ++tt) {
                const int f = tt * 16 + c;
                float x = acc[tt][r] + base0[f] + tab1[f];
                if (p) x += tab2[f];
                x = fmaxf(x, 0.f);
                const float4 w4 = *(const float4*)(W2 + f * 4);
                p0 += x * w4.x; p1 += x * w4.y; p2 += x * w4.z; p3 += x * w4.w;
            }
#pragma unroll
            for (int m = 1; m < 16; m <<= 1) {
                p0 += __shfl_xor(p0, m); p1 += __shfl_xor(p1, m);
                p2 += __shfl_xor(p2, m); p3 += __shfl_xor(p3, m);
            }
            if (c == 0) {
                float m0 = 1.f, m1 = 1.f, m2 = 1.f, m3 = 1.f;
                if (p == 1) {
                    const float4 hs = *(const float4*)(head_sister + (size_t)node * 4);
                    m0 = hs.x; m1 = hs.y; m2 = hs.z; m3 = hs.w;
                } else if (p == 2) {
                    const float4 ts = *(const float4*)(tail_sister + (size_t)node * 4);
                    m0 = ts.x; m1 = ts.y; m2 = ts.z; m3 = ts.w;
                }
                float4 o;
                o.x = sigmoidf_(p0 + b2[0]) * m0;
                o.y = sigmoidf_(p1 + b2[1]) * m1;
                o.z = sigmoidf_(p2 + b2[2]) * m2;
                o.w = sigmoidf_(p3 + b2[3]) * m3;
                *(float4*)&wv[p][nb][0] = o;
            }
        }
    }
    __syncthreads();

    // ---- den partials (12 threads) ----
    if (t < 12) {
        const int p = t >> 2, l = t & 3;
        float s = 0.f;
        for (int n = 0; n < 64; ++n) s += wv[p][n][l];
        atomicAdd(&den[g * 12 + t], s);
    }

    // ---- num partials: thread t owns features 2t, 2t+1 ----
    {
        const int f0 = t * 2;
        const int l0 = f0 >> 7;
        float s00=0.f, s01=0.f, s10=0.f, s11=0.f, s20=0.f, s21=0.f;
        for (int n = 0; n < 64; ++n) {
            unsigned xv = *(const unsigned*)((const char*)xa + n * 1024 + ((f0 * 2) ^ ((n & 7) << 4)));
            float x0 = bf2f((unsigned short)(xv & 0xffff));
            float x1 = bf2f((unsigned short)(xv >> 16));
            float w0 = wv[0][n][l0], w1 = wv[1][n][l0], w2 = wv[2][n][l0];
            s00 += w0 * x0; s01 += w0 * x1;
            s10 += w1 * x0; s11 += w1 * x1;
            s20 += w2 * x0; s21 += w2 * x1;
        }
        float* numg = num + (size_t)g * 3 * 512;
        atomicAdd(&numg[0 * 512 + f0], s00); atomicAdd(&numg[0 * 512 + f0 + 1], s01);
        atomicAdd(&numg[1 * 512 + f0], s10); atomicAdd(&numg[1 * 512 + f0 + 1], s11);
        atomicAdd(&numg[2 * 512 + f0], s20); atomicAdd(&numg[2 * 512 + f0 + 1], s21);
    }
}

// ---------------- K3: finalize means -------------------------------------
__launch_bounds__(256)
__global__ void k_finalize(const float* __restrict__ num, const float* __restrict__ den,
                           float* __restrict__ g_out, float* __restrict__ ghs,
                           float* __restrict__ gts) {
    __shared__ float dsm[12];
    const int g = blockIdx.x, t = threadIdx.x;
    if (t < 12) dsm[t] = den[g * 12 + t];
    __syncthreads();
    const float* numg = num + (size_t)g * 3 * 512;
    for (int f = t; f < 512; f += 256) {
        const int l = f >> 7;
        g_out[g * 512 + f] = numg[0 * 512 + f] / dsm[l];
        ghs[g * 512 + f]   = numg[1 * 512 + f] / dsm[4 + l];
        gts[g * 512 + f]   = numg[2 * 512 + f] / dsm[8 + l];
    }
}

// ---------------- K4: build g_ht (bf16) ----------------------------------
__launch_bounds__(256)
__global__ void k_build_ght(const float* __restrict__ ghs, const float* __restrict__ gts,
                            const float* __restrict__ hN, const float* __restrict__ tN,
                            const float* __restrict__ sh, const float* __restrict__ st,
                            const int* __restrict__ rel_labels, unsigned short* __restrict__ ght) {
    const int g = blockIdx.x, t = threadIdx.x;
    const int rel = rel_labels[g];
    for (int i = t; i < 3200; i += 256) {
        float v;
        if      (i < 512)  v = ghs[g * 512 + i] * hN[g * 512 + i];
        else if (i < 1024) { int j = i - 512;  v = gts[g * 512 + j] * tN[g * 512 + j]; }
        else if (i < 1536) v = ghs[g * 512 + i - 1024];
        else if (i < 2048) v = gts[g * 512 + i - 1536];
        else if (i < 2560) v = hN[g * 512 + i - 2048];
        else if (i < 3072) v = tN[g * 512 + i - 2560];
        else if (i < 3136) v = sh[rel * 64 + i - 3072];
        else               v = st[rel * 64 + i - 3136];
        ght[g * 3200 + i] = f2bf(v);
    }
}

// ---------------- K5: ht GEMM (MFMA): [512,3200]@[3200,512] + relu -------
__launch_bounds__(256)
__global__ void k_ht_gemm(const unsigned short* __restrict__ ght, const unsigned short* __restrict__ htwT,
                          const float* __restrict__ ht_b, float* __restrict__ ht_out) {
    const int lane = threadIdx.x & 63;
    const int wave = threadIdx.x >> 6;
    const int c = lane & 15, grp = lane >> 4;
    const int rowBase = blockIdx.x * 64 + wave * 16;
    const int colBase = blockIdx.y * 64;
    const unsigned short* ap = ght  + (size_t)(rowBase + c) * 3200 + grp * 8;
    const unsigned short* bp = htwT + (size_t)(colBase + c) * 3200 + grp * 8;
    f32x4 acc[4];
#pragma unroll
    for (int t = 0; t < 4; ++t) { acc[t][0]=0.f; acc[t][1]=0.f; acc[t][2]=0.f; acc[t][3]=0.f; }
#pragma unroll 2
    for (int ks = 0; ks < 100; ++ks) {
        bf16x8 af = *(const bf16x8*)(ap + ks * 32);
#pragma unroll
        for (int t = 0; t < 4; ++t) {
            bf16x8 bv = *(const bf16x8*)(bp + ks * 32 + t * (16 * 3200));
            acc[t] = __builtin_amdgcn_mfma_f32_16x16x32_bf16(af, bv, acc[t], 0, 0, 0);
        }
    }
#pragma unroll
    for (int t = 0; t < 4; ++t) {
        const int col = colBase + t * 16 + c;
        const float bias = ht_b[col];
#pragma unroll
        for (int r = 0; r < 4; ++r) {
            const int row = rowBase + grp * 4 + r;
            ht_out[row * 512 + col] = fmaxf(acc[t][r] + bias, 0.f);
        }
    }
}

// ---------------- K6: fc + out -------------------------------------------
__launch_bounds__(128)
__global__ void k_fc(const float* __restrict__ g_out, const float* __restrict__ hN,
                     const float* __restrict__ tN, const float* __restrict__ ht_out,
                     const float* __restrict__ rel_emb, const int* __restrict__ rel_labels,
                     const float* __restrict__ fc_w, const float* __restrict__ fc_b,
                     const float* __restrict__ out_w, const float* __restrict__ out_b,
                     float* __restrict__ outp) {
    __shared__ float red[128];
    const int g = blockIdx.x, t = threadIdx.x;
    const int o = t & 15, ch = t >> 4;    // 8 chunks of 264
    const int rel = rel_labels[g];
    float p = 0.f;
    for (int i = ch * 264; i < ch * 264 + 264; ++i) {
        float v;
        if      (i < 512)  v = g_out[g * 512 + i];
        else if (i < 1024) v = hN[g * 512 + i - 512];
        else if (i < 1536) v = tN[g * 512 + i - 1024];
        else if (i < 2048) v = ht_out[g * 512 + i - 1536];
        else               v = rel_emb[rel * 64 + i - 2048];
        p += v * fc_w[i * 16 + o];
    }
    red[t] = p;
    __syncthreads();
    if (t < 16) {
        float s = fc_b[t];
        for (int c2 = 0; c2 < 8; ++c2) s += red[c2 * 16 + t];
        red[t] = fmaxf(s, 0.f) * out_w[t];
    }
    __syncthreads();
    if (t == 0) {
        float s = out_b[0];
        for (int i = 0; i < 16; ++i) s += red[i];
        outp[g] = s;
    }
}

// ---------------- launch --------------------------------------------------
extern "C" void kernel_launch(void* const* d_in, const int* in_sizes, int n_in,
                              void* d_out, int out_size, void* d_ws, size_t ws_size,
                              hipStream_t stream) {
    const float* node_repr   = (const float*)d_in[0];
    const float* head_sister = (const float*)d_in[1];
    const float* tail_sister = (const float*)d_in[2];
    const int*   t_label     = (const int*)d_in[3];
    const int*   hs_type     = (const int*)d_in[4];
    const int*   ts_type     = (const int*)d_in[5];
    const int*   head_ids    = (const int*)d_in[7];
    const int*   tail_ids    = (const int*)d_in[8];
    const int*   rel_labels  = (const int*)d_in[9];
    const float* rel_emb     = (const float*)d_in[10];
    const float* sim_head    = (const float*)d_in[11];
    const float* sim_tail    = (const float*)d_in[12];
    const float* A_w  = (const float*)d_in[13];
    const float* A_b  = (const float*)d_in[14];
    const float* B_w  = (const float*)d_in[15];
    const float* B_b  = (const float*)d_in[16];
    const float* C_w  = (const float*)d_in[17];
    const float* C_b  = (const float*)d_in[18];
    const float* Dm_w = (const float*)d_in[19];
    const float* Dm_b = (const float*)d_in[20];
    const float* E_w  = (const float*)d_in[21];
    const float* E_b  = (const float*)d_in[22];
    const float* G_w  = (const float*)d_in[23];
    const float* G_b  = (const float*)d_in[24];
    const float* ht_w = (const float*)d_in[25];
    const float* ht_b = (const float*)d_in[26];
    const float* fc_w = (const float*)d_in[27];
    const float* fc_b = (const float*)d_in[28];
    const float* out_w = (const float*)d_in[29];
    const float* out_b = (const float*)d_in[30];
    float* out = (float*)d_out;

    char* ws = (char*)d_ws;
    size_t off = 0;
    auto take = [&](size_t bytes) -> void* {
        void* p = ws + off;
        off += (bytes + 255) & ~(size_t)255;
        return p;
    };
    unsigned short* WT   = (unsigned short*)take((size_t)384 * 512 * 2);
    unsigned short* htwT = (unsigned short*)take((size_t)512 * 3200 * 2);
    float* EmbA = (float*)take(51 * 128 * 4);
    float* T1h  = (float*)take(51 * 128 * 4);
    float* T2h  = (float*)take(51 * 128 * 4);
    float* T1t  = (float*)take(51 * 128 * 4);
    float* T2t  = (float*)take(51 * 128 * 4);
    float* hN   = (float*)take((size_t)Bg * 512 * 4);
    float* tN   = (float*)take((size_t)Bg * 512 * 4);
    float* gHT  = (float*)take((size_t)Bg * 128 * 4);
    float* dHT  = (float*)take((size_t)Bg * 128 * 4);
    float* num  = (float*)take((size_t)Bg * 3 * 512 * 4);   // zeroed below
    float* den  = (float*)take((size_t)Bg * 12 * 4);        // contiguous w/ num
    float* g_out_ = (float*)take((size_t)Bg * 512 * 4);
    float* ghs  = (float*)take((size_t)Bg * 512 * 4);
    float* gts  = (float*)take((size_t)Bg * 512 * 4);
    unsigned short* ght = (unsigned short*)take((size_t)Bg * 3200 * 2);
    float* ht_out = (float*)take((size_t)Bg * 512 * 4);
    (void)ws_size; (void)in_sizes; (void)n_in; (void)out_size;

    k_tables<<<dim3(51, 5), 128, 0, stream>>>(rel_emb, sim_head, sim_tail, A_w, C_w, E_w,
                                              EmbA, T1h, T2h, T1t, T2t);
    k_pack_wt<<<768, 256, 0, stream>>>(A_w, C_w, E_w, WT);
    k_pack_htw<<<dim3(100, 16), 256, 0, stream>>>(ht_w, htwT);
    k_gather_ht<<<Bg, 512, 0, stream>>>(node_repr, head_ids, tail_ids, hN, tN);
    k_ht_gates<<<Bg / 2, 256, 0, stream>>>(hN, tN, C_w, C_b, E_w, E_b, gHT, dHT);
    hipMemsetAsync(num, 0, (size_t)Bg * 3 * 512 * 4 + (size_t)Bg * 12 * 4, stream);
    k_gates_fused<<<NN / 64, 256, 0, stream>>>(node_repr, WT, EmbA, T1h, T2h, T1t, T2t,
                                               gHT, dHT, A_b, B_w, B_b, Dm_w, Dm_b, G_w, G_b,
                                               t_label, hs_type, ts_type,
                                               head_sister, tail_sister, num, den);
    k_finalize<<<Bg, 256, 0, stream>>>(num, den, g_out_, ghs, gts);
    k_build_ght<<<Bg, 256, 0, stream>>>(ghs, gts, hN, tN, sim_head, sim_tail, rel_labels, ght);
    k_ht_gemm<<<dim3(8, 8), 256, 0, stream>>>(ght, htwT, ht_b, ht_out);
    k_fc<<<Bg, 128, 0, stream>>>(g_out_, hN, tN, ht_out, rel_emb, rel_labels,
                                 fc_w, fc_b, out_w, out_b, out);
}